// Round 3
// baseline (53.219 us; speedup 1.0000x reference)
//
#include <hip/hip_runtime.h>
#include <math.h>

#define D4 32          // 128 floats / 4 per float4
#define KTOT 256
#define TN 32          // nodes per block
#define TK 128         // centroids per block (K half)

// ws layout: [0] u32 completion counter (any start value works: election is
// old % nblk == nblk-1 and every call adds exactly nblk); [256..] f32 partials
// part[bn][KTOT] (each (bn,kh) block fills its 128-k half).
__global__ __launch_bounds__(256) void scd_fused(
    const float* __restrict__ node,
    const float* __restrict__ maskp,
    const float* __restrict__ cw,
    const float* __restrict__ cptr,
    float* __restrict__ out,
    unsigned* __restrict__ ws_cnt,
    float* __restrict__ part,
    int nbn, int maskN)
{
    __shared__ float4 xs[TN][D4];
    __shared__ float x2_s[TN];
    __shared__ float scale_s[TK];
    __shared__ float y2_s[TK];
    __shared__ int lastblk;
    __shared__ float wred[4];

    const int tid = threadIdx.x;
    const int bn = blockIdx.x >> 1;
    const int kh = blockIdx.x & 1;
    const int nb = bn * TN;
    const int kb = kh * TK;
    const int nblk = nbn * 2;
    const float c = cptr[0];

    // ---- stage x tile into LDS (XOR-swizzled on float4 chunk index) ----
    const float4* nf4 = (const float4*)(node + (size_t)nb * 128);
    #pragma unroll
    for (int it = 0; it < (TN * D4) / 256; ++it) {
        int e = tid + 256 * it;
        int n = e >> 5;
        int cc = e & 31;
        xs[n][cc ^ ((n >> 2) & 7)] = nf4[e];
    }

    // ---- per-centroid projection scale + projected y2 for this K-half ----
    if (tid < TK) {
        int k = kb + tid;
        const float4* yr = (const float4*)(cw + (size_t)k * 128);
        float ss = 0.f;
        #pragma unroll 8
        for (int q = 0; q < D4; ++q) {
            float4 v = yr[q];
            ss += v.x * v.x + v.y * v.y + v.z * v.z + v.w * v.w;
        }
        float norm = fmaxf(sqrtf(ss), 1e-15f);
        float maxn = (1.0f - 4e-3f) / sqrtf(c);
        float sc = (norm > maxn) ? (maxn / norm) : 1.0f;
        scale_s[tid] = sc;
        y2_s[tid] = ss * sc * sc;
    }
    __syncthreads();

    // ---- x2 per node (8 threads per node) ----
    {
        int n = tid >> 3, q = tid & 7;
        float p = 0.f;
        #pragma unroll
        for (int cc = q * 4; cc < q * 4 + 4; ++cc) {
            float4 v = xs[n][cc ^ ((n >> 2) & 7)];
            p += v.x * v.x + v.y * v.y + v.z * v.z + v.w * v.w;
        }
        p += __shfl_xor(p, 1);
        p += __shfl_xor(p, 2);
        p += __shfl_xor(p, 4);
        if (q == 0) x2_s[n] = p;
    }
    __syncthreads();

    // ---- pairwise dot products: 4 nodes x 4 centroids per thread ----
    const int ng = tid & 7;   // node group 0..7  -> nodes 4*ng..4*ng+3
    const int kg = tid >> 3;  // k group 0..31    -> ks kb+4*kg..+3

    float acc[4][4];
    #pragma unroll
    for (int i = 0; i < 4; ++i)
        #pragma unroll
        for (int j = 0; j < 4; ++j) acc[i][j] = 0.f;

    const float* ybase = cw + (size_t)(kb + 4 * kg) * 128;

    #pragma unroll 4
    for (int cc = 0; cc < D4; ++cc) {
        float4 xv[4], yv[4];
        #pragma unroll
        for (int i = 0; i < 4; ++i) xv[i] = xs[4 * ng + i][cc ^ (ng & 7)];
        #pragma unroll
        for (int j = 0; j < 4; ++j) yv[j] = *(const float4*)(ybase + (size_t)j * 128 + cc * 4);
        #pragma unroll
        for (int i = 0; i < 4; ++i)
            #pragma unroll
            for (int j = 0; j < 4; ++j) {
                acc[i][j] += xv[i].x * yv[j].x;
                acc[i][j] += xv[i].y * yv[j].y;
                acc[i][j] += xv[i].z * yv[j].z;
                acc[i][j] += xv[i].w * yv[j].w;
            }
    }

    // ---- epilogue: hyperbolic sqdist, float4 stores, column partials ----
    const float sqrt_c = __builtin_amdgcn_sqrtf(c);
    // artanh via log2: 0.5*ln(r) = 0.5*ln2*log2(r); fold into 2/sqrt_c
    const float dscale = (2.0f / sqrt_c) * 0.34657359028f; // 0.5*ln2 * 2/sqrt_c
    const float twoc = 2.0f * c;
    const float cc2 = c * c;

    float x2r[4], br[4];
    #pragma unroll
    for (int i = 0; i < 4; ++i) {
        x2r[i] = x2_s[4 * ng + i];
        br[i] = 1.0f - c * x2r[i];
    }

    float sv[4][4];   // s[i][j]
    float ks[4];      // column partial per j

    #pragma unroll
    for (int j = 0; j < 4; ++j) {
        int kk = 4 * kg + j;
        float sc = scale_s[kk];
        float y2 = y2_s[kk];
        float abase = 1.0f + c * y2;
        float ccy2 = cc2 * y2;
        float kacc = 0.f;
        #pragma unroll
        for (int i = 0; i < 4; ++i) {
            float x2 = x2r[i];
            float b = br[i];
            float xy = -acc[i][j] * sc;             // dot(-x, y_proj)
            float a = fmaf(twoc, xy, abase);        // 1 + 2c·xy + c·y2
            float den = fmaf(twoc, xy, fmaf(ccy2, x2, 1.0f));
            float num2 = fmaf(a * a, x2, fmaf(b * b, y2, 2.0f * a * b * xy));
            num2 = fmaxf(num2, 0.0f);
            den = fmaxf(den, 1e-15f);
            float z = sqrt_c * __builtin_amdgcn_sqrtf(num2) * __builtin_amdgcn_rcpf(den);
            z = fminf(fmaxf(z, 0.0f), 0.99999994f);
            float arg = (1.0f + z) * __builtin_amdgcn_rcpf(1.0f - z);
            float d = dscale * __builtin_amdgcn_logf(arg);   // log2
            float s = d * d;
            sv[i][j] = s;
            kacc += s;
        }
        ks[j] = kacc;
    }

    // coalesced float4 stores of the distance tile
    #pragma unroll
    for (int i = 0; i < 4; ++i) {
        float4 v = make_float4(sv[i][0], sv[i][1], sv[i][2], sv[i][3]);
        *(float4*)(out + KTOT + (size_t)(nb + 4 * ng + i) * KTOT + kb + 4 * kg) = v;
    }

    // reduce column partials over the 8 node-groups (ng = low 3 lane bits)
    #pragma unroll
    for (int j = 0; j < 4; ++j) {
        ks[j] += __shfl_xor(ks[j], 1);
        ks[j] += __shfl_xor(ks[j], 2);
        ks[j] += __shfl_xor(ks[j], 4);
    }
    if (ng == 0) {
        float* pp = part + (size_t)bn * KTOT + kb + 4 * kg;
        #pragma unroll
        for (int j = 0; j < 4; ++j)
            __hip_atomic_store(pp + j, ks[j], __ATOMIC_RELAXED, __HIP_MEMORY_SCOPE_AGENT);
    }

    // ---- completion count; last block finalizes ----
    __syncthreads();   // drains vmem (sc1 stores globally visible once retired)
    if (tid == 0) {
        unsigned old = __hip_atomic_fetch_add(ws_cnt, 1u, __ATOMIC_ACQ_REL, __HIP_MEMORY_SCOPE_AGENT);
        lastblk = (old % (unsigned)nblk) == (unsigned)(nblk - 1);
    }
    __syncthreads();
    if (!lastblk) return;

    // ---- finalize (single block): mask sum + column totals ----
    float p = 0.f;
    {
        const float4* m4 = (const float4*)maskp;
        int m4n = maskN >> 2;
        for (int i2 = tid; i2 < m4n; i2 += 256) {
            float4 v = m4[i2];
            p += v.x + v.y + v.z + v.w;
        }
        #pragma unroll
        for (int st = 32; st > 0; st >>= 1) p += __shfl_xor(p, st);
        if ((tid & 63) == 0) wred[tid >> 6] = p;
    }
    __syncthreads();
    float msum = wred[0] + wred[1] + wred[2] + wred[3];
    float inv = 1.0f / msum;

    // column k = tid; fixed-order sum over bn (deterministic); 4 accumulators
    float s0 = 0.f, s1 = 0.f, s2 = 0.f, s3 = 0.f;
    const float* pc = part + tid;
    int b2 = 0;
    for (; b2 + 3 < nbn; b2 += 4) {
        s0 += __hip_atomic_load(pc + (size_t)(b2 + 0) * KTOT, __ATOMIC_RELAXED, __HIP_MEMORY_SCOPE_AGENT);
        s1 += __hip_atomic_load(pc + (size_t)(b2 + 1) * KTOT, __ATOMIC_RELAXED, __HIP_MEMORY_SCOPE_AGENT);
        s2 += __hip_atomic_load(pc + (size_t)(b2 + 2) * KTOT, __ATOMIC_RELAXED, __HIP_MEMORY_SCOPE_AGENT);
        s3 += __hip_atomic_load(pc + (size_t)(b2 + 3) * KTOT, __ATOMIC_RELAXED, __HIP_MEMORY_SCOPE_AGENT);
    }
    for (; b2 < nbn; ++b2)
        s0 += __hip_atomic_load(pc + (size_t)b2 * KTOT, __ATOMIC_RELAXED, __HIP_MEMORY_SCOPE_AGENT);
    out[tid] = ((s0 + s1) + (s2 + s3)) * inv;
}

extern "C" void kernel_launch(void* const* d_in, const int* in_sizes, int n_in,
                              void* d_out, int out_size, void* d_ws, size_t ws_size,
                              hipStream_t stream) {
    const float* node = (const float*)d_in[0];
    const float* mask = (const float*)d_in[1];
    const float* cw   = (const float*)d_in[2];
    const float* cp   = (const float*)d_in[3];
    float* out = (float*)d_out;
    unsigned* cnt = (unsigned*)d_ws;
    float* part = (float*)d_ws + 256;   // [nbn][KTOT]

    int N = in_sizes[0] / 128;
    int maskN = in_sizes[1];
    int nbn = N / TN;

    scd_fused<<<dim3(nbn * 2), 256, 0, stream>>>(node, mask, cw, cp, out, cnt, part, nbn, maskN);
}

// Round 4
// 23.519 us; speedup vs baseline: 2.2628x; 2.2628x over previous
//
#include <hip/hip_runtime.h>
#include <math.h>

#define D4 32          // 128 floats / 4 per float4
#define KTOT 256
#define TN 64          // nodes per block
#define TK 64          // centroids per block
// grid = (N/TN) * (KTOT/TK); bn = blockIdx>>2, kq = blockIdx&3

__global__ __launch_bounds__(256) void scd_main(
    const float* __restrict__ node,
    const float* __restrict__ cw,
    const float* __restrict__ cptr,
    float* __restrict__ out,
    float* __restrict__ ws_part,
    int nbn)
{
    __shared__ float4 xs[TN][D4];
    __shared__ float4 ys[TK][D4];
    __shared__ float x2_s[TN];
    __shared__ float scale_s[TK];
    __shared__ float y2_s[TK];

    const int tid = threadIdx.x;
    const int bn = blockIdx.x >> 2;
    const int kq = blockIdx.x & 3;
    const int nb = bn * TN;
    const int kb = kq * TK;
    const float c = cptr[0];

    // ---- stage x and y tiles into LDS, XOR-swizzled on chunk index ----
    // row r chunk cc stored at [r][cc ^ ((r>>2)&7)] — main-loop reads are
    // conflict-free (distinct row-quads land on distinct bank quads)
    const float4* nf4 = (const float4*)(node + (size_t)nb * 128);
    const float4* yf4 = (const float4*)(cw + (size_t)kb * 128);
    #pragma unroll
    for (int it = 0; it < 8; ++it) {
        int e = tid + 256 * it;
        int r = e >> 5, cc = e & 31;
        xs[r][cc ^ ((r >> 2) & 7)] = nf4[e];
    }
    #pragma unroll
    for (int it = 0; it < 8; ++it) {
        int e = tid + 256 * it;
        int r = e >> 5, cc = e & 31;
        ys[r][cc ^ ((r >> 2) & 7)] = yf4[e];
    }

    // ---- per-centroid projection scale + projected y2 (from global, L2-hot) ----
    if (tid < TK) {
        int k = kb + tid;
        const float4* yr = (const float4*)(cw + (size_t)k * 128);
        float ss = 0.f;
        #pragma unroll 8
        for (int q = 0; q < D4; ++q) {
            float4 v = yr[q];
            ss += v.x * v.x + v.y * v.y + v.z * v.z + v.w * v.w;
        }
        float norm = fmaxf(sqrtf(ss), 1e-15f);
        float maxn = (1.0f - 4e-3f) / sqrtf(c);
        float sc = (norm > maxn) ? (maxn / norm) : 1.0f;
        scale_s[tid] = sc;
        y2_s[tid] = ss * sc * sc;
    }
    __syncthreads();

    // ---- x2 per node (4 threads per node, 8 chunks each) ----
    {
        int n = tid >> 2, q = tid & 3;
        int key = (n >> 2) & 7;
        float p = 0.f;
        #pragma unroll
        for (int m = 0; m < 8; ++m) {
            float4 v = xs[n][(q * 8 + m) ^ key];
            p += v.x * v.x + v.y * v.y + v.z * v.z + v.w * v.w;
        }
        p += __shfl_xor(p, 1);
        p += __shfl_xor(p, 2);
        if (q == 0) x2_s[n] = p;
    }
    __syncthreads();

    // ---- pairwise dots: 4 nodes x 4 centroids per thread, LDS-only loop ----
    const int ng = tid & 15;   // node group: rows 4*ng..4*ng+3
    const int kg = tid >> 4;   // k group:   cols 4*kg..4*kg+3
    const int xkey = ng & 7;   // swizzle key for rows 4ng+i  ((r>>2)&7 = ng&7)
    const int ykey = kg & 7;   // swizzle key for rows 4kg+j

    float acc[4][4];
    #pragma unroll
    for (int i = 0; i < 4; ++i)
        #pragma unroll
        for (int j = 0; j < 4; ++j) acc[i][j] = 0.f;

#define LOADX(dst, cc) { _Pragma("unroll") for (int i = 0; i < 4; ++i) dst[i] = xs[4*ng+i][(cc) ^ xkey]; }
#define LOADY(dst, cc) { _Pragma("unroll") for (int j = 0; j < 4; ++j) dst[j] = ys[4*kg+j][(cc) ^ ykey]; }
#define FMA16(xv, yv) { _Pragma("unroll") for (int i = 0; i < 4; ++i) _Pragma("unroll") for (int j = 0; j < 4; ++j) { \
        acc[i][j] = fmaf(xv[i].x, yv[j].x, acc[i][j]); \
        acc[i][j] = fmaf(xv[i].y, yv[j].y, acc[i][j]); \
        acc[i][j] = fmaf(xv[i].z, yv[j].z, acc[i][j]); \
        acc[i][j] = fmaf(xv[i].w, yv[j].w, acc[i][j]); } }

    {
        float4 xa[4], ya[4], xb[4], yb[4];
        LOADX(xa, 0); LOADY(ya, 0);
        #pragma unroll
        for (int cc = 0; cc < D4; cc += 2) {
            LOADX(xb, cc + 1); LOADY(yb, cc + 1);
            FMA16(xa, ya);
            if (cc + 2 < D4) { LOADX(xa, cc + 2); LOADY(ya, cc + 2); }
            FMA16(xb, yb);
        }
    }

    // ---- epilogue: hyperbolic sqdist, float4 stores, column partials ----
    const float sqrt_c = __builtin_amdgcn_sqrtf(c);
    const float dscale = (2.0f / sqrt_c) * 0.34657359028f; // 0.5*ln2 * 2/sqrt_c (artanh via log2)
    const float twoc = 2.0f * c;
    const float cc2 = c * c;

    float x2r[4], br[4];
    #pragma unroll
    for (int i = 0; i < 4; ++i) {
        x2r[i] = x2_s[4 * ng + i];
        br[i] = 1.0f - c * x2r[i];
    }

    float sv[4][4];
    float ks[4];

    #pragma unroll
    for (int j = 0; j < 4; ++j) {
        int kk = 4 * kg + j;
        float sc = scale_s[kk];
        float y2 = y2_s[kk];
        float abase = 1.0f + c * y2;
        float ccy2 = cc2 * y2;
        float kacc = 0.f;
        #pragma unroll
        for (int i = 0; i < 4; ++i) {
            float x2 = x2r[i];
            float b = br[i];
            float xy = -acc[i][j] * sc;             // dot(-x, y_proj)
            float a = fmaf(twoc, xy, abase);        // 1 + 2c·xy + c·y2
            float den = fmaf(twoc, xy, fmaf(ccy2, x2, 1.0f));
            float num2 = fmaf(a * a, x2, fmaf(b * b, y2, 2.0f * a * b * xy));
            num2 = fmaxf(num2, 0.0f);
            den = fmaxf(den, 1e-15f);
            float z = sqrt_c * __builtin_amdgcn_sqrtf(num2) * __builtin_amdgcn_rcpf(den);
            z = fminf(fmaxf(z, 0.0f), 0.99999994f);
            float arg = (1.0f + z) * __builtin_amdgcn_rcpf(1.0f - z);
            float d = dscale * __builtin_amdgcn_logf(arg);   // log2
            float s = d * d;
            sv[i][j] = s;
            kacc += s;
        }
        ks[j] = kacc;
    }

    // coalesced float4 stores of the distance tile
    #pragma unroll
    for (int i = 0; i < 4; ++i) {
        float4 v = make_float4(sv[i][0], sv[i][1], sv[i][2], sv[i][3]);
        *(float4*)(out + KTOT + (size_t)(nb + 4 * ng + i) * KTOT + kb + 4 * kg) = v;
    }

    // reduce column partials over the 16 node-groups (ng = low 4 lane bits)
    #pragma unroll
    for (int j = 0; j < 4; ++j) {
        ks[j] += __shfl_xor(ks[j], 1);
        ks[j] += __shfl_xor(ks[j], 2);
        ks[j] += __shfl_xor(ks[j], 4);
        ks[j] += __shfl_xor(ks[j], 8);
    }
    if (ng == 0) {
        // transposed: ws_part[k][bn] for coalesced finalize reads
        float* pp = ws_part + (size_t)(kb + 4 * kg) * nbn + bn;
        #pragma unroll
        for (int j = 0; j < 4; ++j) pp[(size_t)j * nbn] = ks[j];
    }
}

// one block per centroid k; thread t owns partial row t (coalesced)
__global__ __launch_bounds__(128) void scd_finalize(
    const float* __restrict__ ws_part,
    const float* __restrict__ mask,
    float* __restrict__ out,
    int nbn, int maskN)
{
    __shared__ float red[128];
    const int tid = threadIdx.x;
    const int k = blockIdx.x;

    // sum(mask) — redundant per block (L2/L3-resident)
    float p = 0.f;
    const float4* m4 = (const float4*)mask;
    int m4n = maskN >> 2;
    for (int i = tid; i < m4n; i += 128) {
        float4 v = m4[i];
        p += v.x + v.y + v.z + v.w;
    }

    // this k's partials, coalesced
    float s = 0.f;
    for (int b = tid; b < nbn; b += 128) s += ws_part[(size_t)k * nbn + b];

    red[tid] = p;
    __syncthreads();
    #pragma unroll
    for (int st = 64; st > 0; st >>= 1) {
        if (tid < st) red[tid] += red[tid + st];
        __syncthreads();
    }
    float msum = red[0];
    __syncthreads();

    red[tid] = s;
    __syncthreads();
    #pragma unroll
    for (int st = 64; st > 0; st >>= 1) {
        if (tid < st) red[tid] += red[tid + st];
        __syncthreads();
    }
    if (tid == 0) out[k] = red[0] / msum;
}

extern "C" void kernel_launch(void* const* d_in, const int* in_sizes, int n_in,
                              void* d_out, int out_size, void* d_ws, size_t ws_size,
                              hipStream_t stream) {
    const float* node = (const float*)d_in[0];
    const float* mask = (const float*)d_in[1];
    const float* cw   = (const float*)d_in[2];
    const float* cp   = (const float*)d_in[3];
    float* out = (float*)d_out;
    float* ws_part = (float*)d_ws;   // [KTOT][N/TN] f32 partials (transposed)

    int N = in_sizes[0] / 128;
    int maskN = in_sizes[1];
    int nbn = N / TN;

    scd_main<<<dim3(nbn * (KTOT / TK)), 256, 0, stream>>>(node, cw, cp, out, ws_part, nbn);
    scd_finalize<<<dim3(KTOT), 128, 0, stream>>>(ws_part, mask, out, nbn, maskN);
}

// Round 5
// 19.734 us; speedup vs baseline: 2.6968x; 1.1918x over previous
//
#include <hip/hip_runtime.h>
#include <hip/hip_bf16.h>
#include <math.h>

#define KTOT 256
#define TN 128         // nodes per block
#define TK 64          // centroids per block
// grid = (N/TN) * (KTOT/TK) = 64 * 4 = 256 blocks, 256 threads (4 waves)

typedef __attribute__((ext_vector_type(8))) short bf16x8;
typedef __attribute__((ext_vector_type(4))) float f32x4;

static __device__ inline bf16x8 pack8(float4 a, float4 b) {
    union { __hip_bfloat162 h[4]; bf16x8 v; } u;
    u.h[0] = __float22bfloat162_rn(make_float2(a.x, a.y));
    u.h[1] = __float22bfloat162_rn(make_float2(a.z, a.w));
    u.h[2] = __float22bfloat162_rn(make_float2(b.x, b.y));
    u.h[3] = __float22bfloat162_rn(make_float2(b.z, b.w));
    return u.v;
}

// ws: [0] u32 completion counter (election via old % nblk — any start value,
// 256 | 2^32 so wraparound-safe); byte 256+: part[nbn][KTOT] f32 partials.
__global__ __launch_bounds__(256) void scd_fused(
    const float* __restrict__ node,
    const float* __restrict__ maskp,
    const float* __restrict__ cw,
    const float* __restrict__ cptr,
    float* __restrict__ out,
    unsigned* __restrict__ cnt,
    float* __restrict__ part,
    int nbn, int nblk, int maskN)
{
    __shared__ short xs[TN][128];   // bf16 bits, 16B-chunk XOR-swizzled
    __shared__ short ys[TK][128];
    __shared__ float x2_s[TN];
    __shared__ float y2r_s[TK], scale_s[TK], y2p_s[TK];
    __shared__ float part_s[4][TK];
    __shared__ int lastblk;

    const int tid = threadIdx.x;
    const int w = tid >> 6;        // wave 0..3
    const int l = tid & 63;        // lane
    const int bn = blockIdx.x >> 2;
    const int kq = blockIdx.x & 3;
    const int nb = bn * TN;
    const int kb = kq * TK;
    const float c = cptr[0];

    // ---- stage X: f32 global -> bf16 LDS (swizzled) + per-row x2 (f32) ----
    const float4* nf4 = (const float4*)(node + (size_t)nb * 128);
    #pragma unroll
    for (int i = 0; i < 8; ++i) {
        int e = tid + 256 * i;
        int r = e >> 4, j = e & 15;
        float4 a = nf4[r * 32 + j * 2];
        float4 b = nf4[r * 32 + j * 2 + 1];
        float p = a.x * a.x + a.y * a.y + a.z * a.z + a.w * a.w
                + b.x * b.x + b.y * b.y + b.z * b.z + b.w * b.w;
        p += __shfl_xor(p, 1);
        p += __shfl_xor(p, 2);
        p += __shfl_xor(p, 4);
        p += __shfl_xor(p, 8);
        if ((tid & 15) == 0) x2_s[r] = p;
        *(bf16x8*)&xs[r][8 * (j ^ (r & 15))] = pack8(a, b);
    }
    // ---- stage Y likewise + raw y2 ----
    const float4* yf4 = (const float4*)(cw + (size_t)kb * 128);
    #pragma unroll
    for (int i = 0; i < 4; ++i) {
        int e = tid + 256 * i;
        int r = e >> 4, j = e & 15;
        float4 a = yf4[r * 32 + j * 2];
        float4 b = yf4[r * 32 + j * 2 + 1];
        float p = a.x * a.x + a.y * a.y + a.z * a.z + a.w * a.w
                + b.x * b.x + b.y * b.y + b.z * b.z + b.w * b.w;
        p += __shfl_xor(p, 1);
        p += __shfl_xor(p, 2);
        p += __shfl_xor(p, 4);
        p += __shfl_xor(p, 8);
        if ((tid & 15) == 0) y2r_s[r] = p;
        *(bf16x8*)&ys[r][8 * (j ^ (r & 15))] = pack8(a, b);
    }
    __syncthreads();

    // ---- projection scale per centroid (no global re-read) ----
    if (tid < TK) {
        float ss = y2r_s[tid];
        float norm = fmaxf(sqrtf(ss), 1e-15f);
        float maxn = (1.0f - 4e-3f) / sqrtf(c);
        float sc = (norm > maxn) ? (maxn / norm) : 1.0f;
        scale_s[tid] = sc;
        y2p_s[tid] = ss * sc * sc;
    }
    __syncthreads();

    // ---- MFMA dot: wave w owns rows 32w..32w+31, all 64 cols ----
    // A/B frag: lane l = row (l&15), k = 8*(l>>4)+idx  (one b128 each)
    const int q = l >> 4;
    const int rA0 = 32 * w + (l & 15);
    const int rA1 = rA0 + 16;
    const int key = l & 15;        // (row&15) for rA0, rA1, and ys rows

    f32x4 acc[2][4];
    #pragma unroll
    for (int sb = 0; sb < 2; ++sb)
        #pragma unroll
        for (int ct = 0; ct < 4; ++ct) acc[sb][ct] = (f32x4){0.f, 0.f, 0.f, 0.f};

    #pragma unroll
    for (int ks = 0; ks < 4; ++ks) {
        int jl = q + 4 * ks;
        bf16x8 A0 = *(bf16x8*)&xs[rA0][8 * (jl ^ key)];
        bf16x8 A1 = *(bf16x8*)&xs[rA1][8 * (jl ^ key)];
        #pragma unroll
        for (int ct = 0; ct < 4; ++ct) {
            bf16x8 B = *(bf16x8*)&ys[16 * ct + (l & 15)][8 * (jl ^ key)];
            acc[0][ct] = __builtin_amdgcn_mfma_f32_16x16x32_bf16(A0, B, acc[0][ct], 0, 0, 0);
            acc[1][ct] = __builtin_amdgcn_mfma_f32_16x16x32_bf16(A1, B, acc[1][ct], 0, 0, 0);
        }
    }

    // ---- epilogue: C/D lane l -> row (l>>4)*4+reg, col (l&15)+16*ct ----
    const float sqrt_c = sqrtf(c);
    const float dscale = (2.0f / sqrt_c) * 0.34657359028f; // 0.5*ln2*2/sqrt_c (artanh via log2)
    const float twoc = 2.0f * c;
    const float cc2 = c * c;

    float scv[4], y2v[4], abase[4], ccy2[4];
    #pragma unroll
    for (int ct = 0; ct < 4; ++ct) {
        int kk = 16 * ct + (l & 15);
        scv[ct] = scale_s[kk];
        y2v[ct] = y2p_s[kk];
        abase[ct] = 1.0f + c * y2v[ct];
        ccy2[ct] = cc2 * y2v[ct];
    }

    float kpart[4] = {0.f, 0.f, 0.f, 0.f};
    #pragma unroll
    for (int sb = 0; sb < 2; ++sb) {
        #pragma unroll
        for (int reg = 0; reg < 4; ++reg) {
            int rloc = 32 * w + 16 * sb + 4 * q + reg;
            float x2 = x2_s[rloc];
            float b = 1.0f - c * x2;
            float* po = out + KTOT + (size_t)(nb + rloc) * KTOT + kb + (l & 15);
            #pragma unroll
            for (int ct = 0; ct < 4; ++ct) {
                float xy = -acc[sb][ct][reg] * scv[ct];
                float a = fmaf(twoc, xy, abase[ct]);
                float den = fmaf(twoc, xy, fmaf(ccy2[ct], x2, 1.0f));
                float num2 = fmaf(a * a, x2, fmaf(b * b, y2v[ct], 2.0f * a * b * xy));
                num2 = fmaxf(num2, 0.0f);
                den = fmaxf(den, 1e-15f);
                float z = sqrt_c * __builtin_amdgcn_sqrtf(num2) * __builtin_amdgcn_rcpf(den);
                z = fminf(fmaxf(z, 0.0f), 0.99999994f);
                float arg = (1.0f + z) * __builtin_amdgcn_rcpf(1.0f - z);
                float d = dscale * __builtin_amdgcn_logf(arg);
                float s = d * d;
                po[16 * ct] = s;
                kpart[ct] += s;
            }
        }
    }

    // ---- column partials: reduce over rows (lane bits 4,5), then waves ----
    #pragma unroll
    for (int ct = 0; ct < 4; ++ct) {
        kpart[ct] += __shfl_xor(kpart[ct], 16);
        kpart[ct] += __shfl_xor(kpart[ct], 32);
    }
    if (l < 16) {
        #pragma unroll
        for (int ct = 0; ct < 4; ++ct) part_s[w][l + 16 * ct] = kpart[ct];
    }
    __syncthreads();
    if (tid < TK) {
        float v = part_s[0][tid] + part_s[1][tid] + part_s[2][tid] + part_s[3][tid];
        // relaxed agent store: write-through to LLC (coherence point), NO L2 flush
        __hip_atomic_store(&part[(size_t)bn * KTOT + kb + tid], v,
                           __ATOMIC_RELAXED, __HIP_MEMORY_SCOPE_AGENT);
    }

    // ---- completion count (relaxed — no cache flush); last block finalizes ----
    __syncthreads();   // compiler drains vmcnt before barrier -> stores at LLC
    if (tid == 0) {
        unsigned old = __hip_atomic_fetch_add(cnt, 1u, __ATOMIC_RELAXED, __HIP_MEMORY_SCOPE_AGENT);
        lastblk = ((old % (unsigned)nblk) == (unsigned)(nblk - 1));
    }
    __syncthreads();
    if (!lastblk) return;

    // ---- elected block: mask sum + column totals (fixed order, deterministic) ----
    float p = 0.f;
    {
        const float4* m4 = (const float4*)maskp;
        int m4n = maskN >> 2;
        for (int i = tid; i < m4n; i += 256) {
            float4 v = m4[i];
            p += v.x + v.y + v.z + v.w;
        }
        p += __shfl_xor(p, 1);  p += __shfl_xor(p, 2);  p += __shfl_xor(p, 4);
        p += __shfl_xor(p, 8);  p += __shfl_xor(p, 16); p += __shfl_xor(p, 32);
    }
    __syncthreads();
    if (l == 0) part_s[0][w] = p;
    __syncthreads();
    float inv = 1.0f / (part_s[0][0] + part_s[0][1] + part_s[0][2] + part_s[0][3]);

    float s0 = 0.f, s1 = 0.f, s2 = 0.f, s3 = 0.f;
    const float* pc = part + tid;
    for (int b = 0; b + 3 < nbn; b += 4) {
        s0 += __hip_atomic_load(pc + (size_t)(b + 0) * KTOT, __ATOMIC_RELAXED, __HIP_MEMORY_SCOPE_AGENT);
        s1 += __hip_atomic_load(pc + (size_t)(b + 1) * KTOT, __ATOMIC_RELAXED, __HIP_MEMORY_SCOPE_AGENT);
        s2 += __hip_atomic_load(pc + (size_t)(b + 2) * KTOT, __ATOMIC_RELAXED, __HIP_MEMORY_SCOPE_AGENT);
        s3 += __hip_atomic_load(pc + (size_t)(b + 3) * KTOT, __ATOMIC_RELAXED, __HIP_MEMORY_SCOPE_AGENT);
    }
    out[tid] = ((s0 + s1) + (s2 + s3)) * inv;
}

extern "C" void kernel_launch(void* const* d_in, const int* in_sizes, int n_in,
                              void* d_out, int out_size, void* d_ws, size_t ws_size,
                              hipStream_t stream) {
    const float* node = (const float*)d_in[0];
    const float* mask = (const float*)d_in[1];
    const float* cw   = (const float*)d_in[2];
    const float* cp   = (const float*)d_in[3];
    float* out = (float*)d_out;
    unsigned* cnt = (unsigned*)d_ws;
    float* part = (float*)((char*)d_ws + 256);   // [nbn][KTOT]

    int N = in_sizes[0] / 128;
    int maskN = in_sizes[1];
    int nbn = N / TN;
    int nblk = nbn * (KTOT / TK);

    scd_fused<<<dim3(nblk), 256, 0, stream>>>(node, mask, cw, cp, out, cnt, part,
                                              nbn, nblk, maskN);
}